// Round 5
// baseline (524.709 us; speedup 1.0000x reference)
//
#include <hip/hip_runtime.h>
#include <cstdint>
#include <cstddef>

// Shapes are fixed by setup_inputs(): T=4096, D=2048, B=2, S=2048.
#define TT 4096
#define DD 2048
#define NH 16
#define HEADD 192
#define NOPE 128
#define VDIM 128
#define SEQ 2048

typedef __bf16 bf16x8 __attribute__((ext_vector_type(8)));
typedef float f32x4 __attribute__((ext_vector_type(4)));
typedef unsigned int u32;

__device__ __forceinline__ float bf2f(unsigned short u) {
    union { unsigned int i; float f; } v; v.i = ((unsigned int)u) << 16; return v.f;
}
__device__ __forceinline__ unsigned short f2bf(float f) {
    union { float f; unsigned int i; } v; v.f = f;
    unsigned int r = v.i + 0x7FFFu + ((v.i >> 16) & 1u);
    return (unsigned short)(r >> 16);
}
__device__ __forceinline__ u32 pack2bf(float a, float b) {
    return (u32)f2bf(a) | ((u32)f2bf(b) << 16);
}
// async global->LDS, 16B per lane; LDS dest = wave-uniform base + lane*16
__device__ __forceinline__ void gload16(const unsigned short* g, unsigned short* l) {
    __builtin_amdgcn_global_load_lds((const __attribute__((address_space(1))) u32*)g,
                                     (__attribute__((address_space(3))) u32*)l, 16, 0, 0);
}

// ---------------- fp32 -> bf16 elementwise ----------------
__global__ __launch_bounds__(256) void cvt_bf16_k(const float* __restrict__ x,
                                                  unsigned short* __restrict__ y, int n) {
    int i = (blockIdx.x * 256 + threadIdx.x) * 4;
    if (i < n) {
        float4 v = *(const float4*)(x + i);
        uint2 o;
        o.x = pack2bf(v.x, v.y);
        o.y = pack2bf(v.z, v.w);
        *(uint2*)(y + i) = o;
    }
}

// ---------------- W[K,N] fp32 -> Wt[N,K] bf16 ----------------
__global__ __launch_bounds__(256) void transpose_cvt_k(const float* __restrict__ W,
                                                       unsigned short* __restrict__ Wt,
                                                       int K, int N) {
    __shared__ float tile[32][33];
    int n0 = blockIdx.x * 32, k0 = blockIdx.y * 32;
    int t = threadIdx.x, lr = t >> 5, lc = t & 31;
#pragma unroll
    for (int p = 0; p < 4; p++) {
        int k = k0 + lr + p * 8, n = n0 + lc;
        tile[lr + p * 8][lc] = (k < K && n < N) ? W[(size_t)k * N + n] : 0.f;
    }
    __syncthreads();
#pragma unroll
    for (int p = 0; p < 4; p++) {
        int n = n0 + lr + p * 8, k = k0 + lc;
        if (n < N && k < K) Wt[(size_t)n * K + k] = f2bf(tile[lc][lr + p * 8]);
    }
}

// ======================================================================
// 128x256 (or 128x192) double-buffered 8-wave GEMM, BK=64.
// Round-5: counted vmcnt (T4). Per K-tile: issue ALL of tile kt+1's loads,
// s_waitcnt vmcnt(NLD) -- waits only for tile kt's (oldest) loads, keeps
// kt+1's in flight across the barrier -- then one setprio MFMA cluster.
// Drain to 0 only on the last tile. Buf reuse gated by the bottom barrier.
// T2 swizzle: element (r,c) stored at col c ^ ((r&7)*8); inverse applied to
// the per-lane GLOBAL source so the linear gload_lds write lands swizzled.
// T1: XCD-clustered block remap (grid % 8 == 0), y-fastest decomposition so
// each XCD pins its B-panel(s) in L2 and streams A.
// ======================================================================
#define GMFMA __builtin_amdgcn_mfma_f32_16x16x32_bf16

template <int BN, typename OT>
__global__ __launch_bounds__(512) void gemm256_k(const unsigned short* __restrict__ A,
                                                 const unsigned short* __restrict__ Bt,
                                                 OT* __restrict__ C,
                                                 int M, int N, int K) {
    constexpr int NREP = BN / 64;            // per-wave N fragments (4 or 3)
    constexpr int NB = BN / 64;              // B 64-row staging chunks
    constexpr int TILE_E = 8192 + BN * 64;   // elements per dbuf (A 128x64 + B BNx64)
    __shared__ __align__(16) unsigned short lds[2 * TILE_E];  // 96KB / 80KB
    const int t = threadIdx.x;
    const int w = t >> 6, lane = t & 63;
    const int wr = w >> 2, wc = w & 3;       // 2M x 4N wave grid; per-wave 64 x BN/4
    const int l15 = lane & 15, quad = lane >> 4;
    // T1: cluster contiguous work per XCD, then y-fastest decompose.
    const int nwg = gridDim.x * gridDim.y;
    const int orig = blockIdx.y * gridDim.x + blockIdx.x;
    const int wg = (orig & 7) * (nwg >> 3) + (orig >> 3);
    const int bxi = wg / gridDim.y, byi = wg - bxi * gridDim.y;
    const int bm = byi * 128, bn = bxi * BN;
    // staging: lane covers row (w*8 + lane>>3) of each 64-row chunk, 16B at
    // inverse-swizzled global col so the linear LDS write lands swizzled
    const int srow = w * 8 + (lane >> 3);
    const int scol = 8 * ((lane & 7) ^ (lane >> 3));
    const unsigned short* Ag = A + (size_t)(bm + srow) * K + scol;
    const unsigned short* Bg = Bt + (size_t)(bn + srow) * K + scol;
    // swizzled read col offsets (elements) for ks=0,1
    const int rc0 = (quad * 8) ^ ((l15 & 7) * 8);
    const int rc1 = (32 + quad * 8) ^ ((l15 & 7) * 8);
    f32x4 acc[4][NREP];
    f32x4 zero = {0.f, 0.f, 0.f, 0.f};
#pragma unroll
    for (int i = 0; i < 4; i++)
#pragma unroll
        for (int n = 0; n < NREP; n++) acc[i][n] = zero;
    const int NT = K >> 6;
    // prologue: stage tile 0 into buf0
    gload16(Ag, &lds[w * 512]);
    gload16(Ag + (size_t)64 * K, &lds[4096 + w * 512]);
#pragma unroll
    for (int c = 0; c < NB; c++)
        gload16(Bg + (size_t)c * 64 * K, &lds[8192 + c * 4096 + w * 512]);

    for (int kt = 0; kt < NT; kt++) {
        const int cb = (kt & 1) * TILE_E;
        const int ob = TILE_E - cb;          // other buffer (tile kt+1)
        if (kt + 1 < NT) {
            // issue ALL of tile kt+1's loads (buf last read in iter kt-1;
            // its readers passed the bottom barrier of kt-1)
            const unsigned short* Agk = Ag + (size_t)(kt + 1) * 64;
            const unsigned short* Bgk = Bg + (size_t)(kt + 1) * 64;
            gload16(Agk, &lds[ob + w * 512]);
            gload16(Agk + (size_t)64 * K, &lds[ob + 4096 + w * 512]);
#pragma unroll
            for (int c = 0; c < NB; c++)
                gload16(Bgk + (size_t)c * 64 * K, &lds[ob + 8192 + c * 4096 + w * 512]);
            // counted gate: outstanding = 2*NLD; wait until only kt+1's remain
            if constexpr (NB == 4) asm volatile("s_waitcnt vmcnt(6)" ::: "memory");
            else                   asm volatile("s_waitcnt vmcnt(5)" ::: "memory");
        } else {
            asm volatile("s_waitcnt vmcnt(0)" ::: "memory");
        }
        __builtin_amdgcn_s_barrier();        // all waves' tile-kt loads resident
        asm volatile("" ::: "memory");
        bf16x8 a[4][2], b[NREP][2];
#pragma unroll
        for (int mi = 0; mi < 4; mi++) {
            int rl = wr * 64 + mi * 16 + l15;
            a[mi][0] = *(const bf16x8*)&lds[cb + rl * 64 + rc0];
            a[mi][1] = *(const bf16x8*)&lds[cb + rl * 64 + rc1];
        }
#pragma unroll
        for (int n = 0; n < NREP; n++) {
            int rl = wc * (BN / 4) + n * 16 + l15;
            b[n][0] = *(const bf16x8*)&lds[cb + 8192 + rl * 64 + rc0];
            b[n][1] = *(const bf16x8*)&lds[cb + 8192 + rl * 64 + rc1];
        }
        __builtin_amdgcn_s_setprio(1);
#pragma unroll
        for (int mi = 0; mi < 4; mi++)
#pragma unroll
            for (int n = 0; n < NREP; n++) {
                acc[mi][n] = GMFMA(a[mi][0], b[n][0], acc[mi][n], 0, 0, 0);
                acc[mi][n] = GMFMA(a[mi][1], b[n][1], acc[mi][n], 0, 0, 0);
            }
        __builtin_amdgcn_s_setprio(0);
        asm volatile("" ::: "memory");
        __builtin_amdgcn_s_barrier();        // buf[kt&1] free for tile kt+2's writes
    }
    // epilogue: C row = bm + wr*64 + mi*16 + quad*4 + r ; col = bn + wc*(BN/4) + n*16 + l15
#pragma unroll
    for (int mi = 0; mi < 4; mi++) {
        int row = bm + wr * 64 + mi * 16 + quad * 4;
#pragma unroll
        for (int n = 0; n < NREP; n++) {
            int col = bn + wc * (BN / 4) + n * 16 + l15;
            OT* cp = C + (size_t)row * N + col;
#pragma unroll
            for (int r = 0; r < 4; r++) {
                float v = acc[mi][n][r];
                if constexpr (sizeof(OT) == 2) cp[(size_t)r * N] = f2bf(v);
                else                            cp[(size_t)r * N] = v;
            }
        }
    }
}

// ---------------- m97-style GEMM, bf16 out, with ldc (used for the 64-col strip) ----
__global__ __launch_bounds__(256) void gemm_bf16o_k(const unsigned short* __restrict__ A,
                                                    const unsigned short* __restrict__ Bt,
                                                    unsigned short* __restrict__ C,
                                                    int M, int N, int K, int ldc) {
    __shared__ __align__(16) unsigned short As[128 * 32];
    __shared__ __align__(16) unsigned short Bs[128 * 32];
    int bm = blockIdx.y * 128, bn = blockIdx.x * 128;
    int t = threadIdx.x;
    int wave = t >> 6, lane = t & 63;
    int wr = (wave >> 1) * 64, wc = (wave & 1) * 64;
    int l15 = lane & 15, quad = lane >> 4;
    f32x4 acc[4][4];
    f32x4 zero = {0.f, 0.f, 0.f, 0.f};
#pragma unroll
    for (int i = 0; i < 4; i++)
#pragma unroll
        for (int j = 0; j < 4; j++) acc[i][j] = zero;
    int r0 = 16 * (2 * wave) + (lane >> 2);
    int cOff = (lane & 3) * 8;
    const unsigned short* gA0 = A + (size_t)(bm + r0) * K + cOff;
    const unsigned short* gA1 = A + (size_t)(bm + r0 + 16) * K + cOff;
    const unsigned short* gB0 = Bt + (size_t)(bn + r0) * K + cOff;
    const unsigned short* gB1 = Bt + (size_t)(bn + r0 + 16) * K + cOff;
    unsigned short* lA0 = &As[(2 * wave) * 512];
    unsigned short* lA1 = &As[(2 * wave + 1) * 512];
    unsigned short* lB0 = &Bs[(2 * wave) * 512];
    unsigned short* lB1 = &Bs[(2 * wave + 1) * 512];
    for (int k0 = 0; k0 < K; k0 += 32) {
        gload16(gA0 + k0, lA0);
        gload16(gA1 + k0, lA1);
        gload16(gB0 + k0, lB0);
        gload16(gB1 + k0, lB1);
        __syncthreads();
        bf16x8 af[4], bfr[4];
#pragma unroll
        for (int i = 0; i < 4; i++)
            af[i] = *(const bf16x8*)&As[(wr + i * 16 + l15) * 32 + quad * 8];
#pragma unroll
        for (int j = 0; j < 4; j++)
            bfr[j] = *(const bf16x8*)&Bs[(wc + j * 16 + l15) * 32 + quad * 8];
#pragma unroll
        for (int i = 0; i < 4; i++)
#pragma unroll
            for (int j = 0; j < 4; j++)
                acc[i][j] = GMFMA(af[i], bfr[j], acc[i][j], 0, 0, 0);
        __syncthreads();
    }
#pragma unroll
    for (int i = 0; i < 4; i++) {
        int row = bm + wr + i * 16 + quad * 4;
#pragma unroll
        for (int j = 0; j < 4; j++) {
            int col = bn + wc + j * 16 + l15;
            if (col < N) {
                unsigned short* cp = C + (size_t)row * ldc + col;
#pragma unroll
                for (int r = 0; r < 4; r++) cp[(size_t)r * ldc] = f2bf(acc[i][j][r]);
            }
        }
    }
}

// Attention-ready padded tiled layouts:
//   Kb2 [bh][kt=32][64 rows][KS_STRIDE=200]
//   Vt2 [bh][kt=32][128 dims][VT_STRIDE=72]
#define KS_STRIDE 200
#define VT_STRIDE 72
#define CS_STRIDE 132

// ---------------- kv GEMM with fused K/V-split epilogue (LDS-bounced stores) -------
__global__ __launch_bounds__(256) void gemm_kv_k(const unsigned short* __restrict__ A,
                                                 const unsigned short* __restrict__ Bt,
                                                 unsigned short* __restrict__ Kb2,
                                                 unsigned short* __restrict__ Vt2) {
    const int K = 512;
    __shared__ __align__(16) unsigned short smem[128 * CS_STRIDE];  // 33.8 KB
    unsigned short* As = smem;              // staging A: 8 KB
    unsigned short* Bs = smem + 128 * 32;   // staging B: 8 KB
    unsigned short* Cs = smem;              // epilogue bounce (reuses staging)
    int bm = blockIdx.y * 128, bn = blockIdx.x * 128;
    int t = threadIdx.x;
    int wave = t >> 6, lane = t & 63;
    int wr = (wave >> 1) * 64, wc = (wave & 1) * 64;
    int l15 = lane & 15, quad = lane >> 4;
    f32x4 acc[4][4];
    f32x4 zero = {0.f, 0.f, 0.f, 0.f};
#pragma unroll
    for (int i = 0; i < 4; i++)
#pragma unroll
        for (int j = 0; j < 4; j++) acc[i][j] = zero;
    int r0 = 16 * (2 * wave) + (lane >> 2);
    int cOff = (lane & 3) * 8;
    const unsigned short* gA0 = A + (size_t)(bm + r0) * K + cOff;
    const unsigned short* gA1 = A + (size_t)(bm + r0 + 16) * K + cOff;
    const unsigned short* gB0 = Bt + (size_t)(bn + r0) * K + cOff;
    const unsigned short* gB1 = Bt + (size_t)(bn + r0 + 16) * K + cOff;
    unsigned short* lA0 = &As[(2 * wave) * 512];
    unsigned short* lA1 = &As[(2 * wave + 1) * 512];
    unsigned short* lB0 = &Bs[(2 * wave) * 512];
    unsigned short* lB1 = &Bs[(2 * wave + 1) * 512];
    for (int k0 = 0; k0 < K; k0 += 32) {
        gload16(gA0 + k0, lA0);
        gload16(gA1 + k0, lA1);
        gload16(gB0 + k0, lB0);
        gload16(gB1 + k0, lB1);
        __syncthreads();
        bf16x8 af[4], bfr[4];
#pragma unroll
        for (int i = 0; i < 4; i++)
            af[i] = *(const bf16x8*)&As[(wr + i * 16 + l15) * 32 + quad * 8];
#pragma unroll
        for (int j = 0; j < 4; j++)
            bfr[j] = *(const bf16x8*)&Bs[(wc + j * 16 + l15) * 32 + quad * 8];
#pragma unroll
        for (int i = 0; i < 4; i++)
#pragma unroll
            for (int j = 0; j < 4; j++)
                acc[i][j] = GMFMA(af[i], bfr[j], acc[i][j], 0, 0, 0);
        __syncthreads();
    }
    // ---- stage output tile in LDS (natural [row][col] layout, padded stride) ----
#pragma unroll
    for (int i = 0; i < 4; i++) {
        int lr = wr + i * 16 + quad * 4;
#pragma unroll
        for (int j = 0; j < 4; j++) {
            int lc = wc + j * 16 + l15;
#pragma unroll
            for (int r = 0; r < 4; r++)
                Cs[(lr + r) * CS_STRIDE + lc] = f2bf(acc[i][j][r]);
        }
    }
    __syncthreads();
    int hh = bn >> 8;
    bool isV = (bn & 255) != 0;
    if (!isV) {
        int row = t >> 1, halfc = t & 1;
        int gs = bm + row;
        int b2 = gs >> 11, s2 = gs & 2047;
        unsigned short* dp = Kb2 +
            ((size_t)((b2 * NH + hh) * 32 + (s2 >> 6)) * 64 + (s2 & 63)) * KS_STRIDE + halfc * 64;
        const unsigned short* sp = &Cs[row * CS_STRIDE + halfc * 64];
#pragma unroll
        for (int g = 0; g < 8; g++)
            *(uint4*)(dp + g * 8) = *(const uint4*)(sp + g * 8);
    } else {
        int kth = t >> 7, dim = t & 127;
        int gs0 = bm + kth * 64;
        int b2 = gs0 >> 11, s20 = gs0 & 2047;
        unsigned short* dp = Vt2 +
            ((size_t)((b2 * NH + hh) * 32 + (s20 >> 6)) * 128 + dim) * VT_STRIDE;
#pragma unroll
        for (int g = 0; g < 8; g++) {
            uint4 o;
            unsigned short* op = (unsigned short*)&o;
#pragma unroll
            for (int q2 = 0; q2 < 8; q2++)
                op[q2] = Cs[(kth * 64 + g * 8 + q2) * CS_STRIDE + dim];
            *(uint4*)(dp + g * 8) = o;
        }
    }
}

// ---------------- broadcast roped k_pe into Kb2 dims [128,192) ----------------
__global__ __launch_bounds__(256) void kpe_fill_k(const unsigned short* __restrict__ kpe,
                                                  unsigned short* __restrict__ Kb2) {
    int trow = blockIdx.x, t = threadIdx.x;
    int b = trow >> 11, s = trow & 2047;
    int kt = s >> 6, sr = s & 63;
    const unsigned short* src = kpe + trow * 64;
#pragma unroll
    for (int i = t; i < NH * 64; i += 256) {
        int h = i >> 6, d = i & 63;
        Kb2[(((size_t)(b * NH + h) * 32 + kt) * 64 + sr) * KS_STRIDE + 128 + d] = src[d];
    }
}

// ---------------- RMSNorm over bf16 input (cols 0..1535 of qab, stride 2112) -------
__global__ __launch_bounds__(256) void rmsnorm_bf_k(const unsigned short* __restrict__ x,
                                                    const float* __restrict__ w,
                                                    unsigned short* __restrict__ y) {
    int row = blockIdx.x, t = threadIdx.x;
    const unsigned short* xr = x + (size_t)row * 2112;
    float s = 0.f;
    for (int i = t; i < 1536; i += 256) { float v = bf2f(xr[i]); s += v * v; }
    __shared__ float red[256];
    red[t] = s; __syncthreads();
    for (int o = 128; o > 0; o >>= 1) { if (t < o) red[t] += red[t + o]; __syncthreads(); }
    float scale = rsqrtf(red[0] / 1536.f + 1e-6f);
    unsigned short* yr = y + (size_t)row * 1536;
    for (int i = t; i < 1536; i += 256) yr[i] = f2bf(bf2f(xr[i]) * scale * w[i]);
}

// ---------------- ckv part of qab (cols 1536..2111): rmsnorm(512) + rope k_pe ------
__global__ __launch_bounds__(256) void kvprep_bf_k(const unsigned short* __restrict__ qab,
                                                   const float* __restrict__ w,
                                                   const float* __restrict__ cosb,
                                                   const float* __restrict__ sinb,
                                                   unsigned short* __restrict__ ckvn,
                                                   unsigned short* __restrict__ kpe) {
    int row = blockIdx.x, t = threadIdx.x;
    const unsigned short* xr = qab + (size_t)row * 2112 + 1536;
    float s = 0.f;
#pragma unroll
    for (int i = t; i < 512; i += 256) { float v = bf2f(xr[i]); s += v * v; }
    __shared__ float red[256];
    red[t] = s; __syncthreads();
    for (int o = 128; o > 0; o >>= 1) { if (t < o) red[t] += red[t + o]; __syncthreads(); }
    float scale = rsqrtf(red[0] / 512.f + 1e-6f);
    unsigned short* yr = ckvn + (size_t)row * 512;
#pragma unroll
    for (int i = t; i < 512; i += 256) yr[i] = f2bf(bf2f(xr[i]) * scale * w[i]);
    if (t < 32) {
        float e = bf2f(xr[512 + 2 * t]), o = bf2f(xr[512 + 2 * t + 1]);
        float c = cosb[row * 32 + t], sn = sinb[row * 32 + t];
        kpe[row * 64 + t]      = f2bf(e * c - o * sn);
        kpe[row * 64 + 32 + t] = f2bf(o * c + e * sn);
    }
}

// ---------------- q bf16 [T,3072] -> Qbuf with rope + 192^-0.5 scale fold ---------
__global__ __launch_bounds__(256) void qprep_bf_k(const unsigned short* __restrict__ q,
                                                  const float* __restrict__ cosb,
                                                  const float* __restrict__ sinb,
                                                  unsigned short* __restrict__ Qb) {
    const float SCALE = 0.07216878364870323f;
    int trow = blockIdx.x, t = threadIdx.x;
    const unsigned short* qr = q + (size_t)trow * (NH * HEADD);
    unsigned short* yr = Qb + (size_t)trow * (NH * HEADD);
    for (int i = t; i < NH * HEADD; i += 256) {
        int h = i / HEADD, d = i - h * HEADD;
        float val;
        if (d < NOPE) val = bf2f(qr[i]);
        else {
            int j = d - NOPE;
            int jj = j & 31;
            const unsigned short* pe = qr + h * HEADD + NOPE;
            float e = bf2f(pe[2 * jj]), o = bf2f(pe[2 * jj + 1]);
            float c = cosb[trow * 32 + jj], sn = sinb[trow * 32 + jj];
            val = (j < 32) ? (e * c - o * sn) : (o * c + e * sn);
        }
        yr[i] = f2bf(val * SCALE);
    }
}

// ---------------- split-K causal flash attention, MFMA bf16, S^T form ----------------
// Round-3 verified version (do not touch): 2 __syncthreads per kt-iter,
// symmetric staging, mask-skip, defer-max, vectorized Opart stores.
__global__ __launch_bounds__(512) void attn_mfma_k(const unsigned short* __restrict__ Qb,
                                                   const unsigned short* __restrict__ Kb2,
                                                   const unsigned short* __restrict__ Vt2,
                                                   unsigned short* __restrict__ Opart,
                                                   float* __restrict__ Mbuf,
                                                   float* __restrict__ Lbuf) {
    __shared__ __align__(16) unsigned short Ks[64 * KS_STRIDE];    // 25.6 KB
    __shared__ __align__(16) unsigned short Vts[128 * VT_STRIDE];  // 18.4 KB
    int xe = 39 - blockIdx.x;
    int h  = blockIdx.y;
    int b  = blockIdx.z;
    int qt = 0, accn = 0;
    while (true) { int c = (qt >> 2) + 1; if (xe < accn + c) break; accn += c; qt++; }
    int chunk = xe - accn;
    int t = threadIdx.x;
    int w = t >> 6, lane = t & 63;
    int l15 = lane & 15, quad = lane >> 4;
    int bh = b * NH + h;
    int q0 = b * SEQ + qt * 128;
    int qglob = qt * 128 + w * 16 + l15;
    int flat = bh * 40 + xe;

    bf16x8 qf[6];
    {
        const unsigned short* qbase = Qb + ((size_t)(q0 + w * 16 + l15) * NH + h) * HEADD + quad * 8;
#pragma unroll
        for (int c = 0; c < 6; c++)
            qf[c] = *(const bf16x8*)(qbase + c * 32);
    }
    f32x4 acc_o[8];
    f32x4 zero = {0.f, 0.f, 0.f, 0.f};
#pragma unroll
    for (int j = 0; j < 8; j++) acc_o[j] = zero;
    float mrun = -1e30f, lrun = 0.f;

    int kt0 = chunk * 8, kt1 = min(kt0 + 7, 2 * qt + 1);
    int cbeg = w * 5 + min(w, 3), cnt = (w < 3) ? 6 : 5;
    for (int kt = kt0; kt <= kt1; kt++) {
        __syncthreads();
        {
            const unsigned short* kg = Kb2 + ((size_t)bh * 32 + kt) * (64 * KS_STRIDE) + lane * 8;
            const unsigned short* vg = Vt2 + ((size_t)bh * 32 + kt) * (128 * VT_STRIDE) + lane * 8;
            for (int c = cbeg; c < cbeg + cnt; c++) {
                if (c < 25) gload16(kg + c * 512, &Ks[c * 512]);
                else        gload16(vg + (c - 25) * 512, &Vts[(c - 25) * 512]);
            }
        }
        __syncthreads();
        f32x4 acc_s[4];
#pragma unroll
        for (int j = 0; j < 4; j++) acc_s[j] = zero;
#pragma unroll
        for (int c = 0; c < 6; c++) {
#pragma unroll
            for (int j = 0; j < 4; j++) {
                bf16x8 kf = *(const bf16x8*)&Ks[(j * 16 + l15) * KS_STRIDE + c * 32 + quad * 8];
                acc_s[j] = GMFMA(kf, qf[c], acc_s[j], 0, 0, 0);
            }
        }
        float sv[4][4];
        const bool needmask = (kt * 64 + 63) > (qt * 128 + w * 16);
        if (needmask) {
#pragma unroll
            for (int j = 0; j < 4; j++) {
                int kbase = kt * 64 + j * 16 + quad * 4;
#pragma unroll
                for (int r = 0; r < 4; r++)
                    sv[j][r] = (kbase + r > qglob) ? -1e30f : acc_s[j][r];
            }
        } else {
#pragma unroll
            for (int j = 0; j < 4; j++)
#pragma unroll
                for (int r = 0; r < 4; r++) sv[j][r] = acc_s[j][r];
        }
        float v = sv[0][0];
#pragma unroll
        for (int j = 0; j < 4; j++)
#pragma unroll
            for (int r = 0; r < 4; r++) v = fmaxf(v, sv[j][r]);
        v = fmaxf(v, __shfl_xor(v, 16));
        v = fmaxf(v, __shfl_xor(v, 32));
        if (!__all(v - mrun <= 8.f)) {
            float mnew = fmaxf(mrun, v);
            float alpha = __expf(mrun - mnew);
            mrun = mnew;
            lrun *= alpha;
#pragma unroll
            for (int jt = 0; jt < 8; jt++)
#pragma unroll
                for (int r = 0; r < 4; r++) acc_o[jt][r] *= alpha;
        }
        float rs = 0.f;
#pragma unroll
        for (int j = 0; j < 4; j++)
#pragma unroll
            for (int r = 0; r < 4; r++) { float p = __expf(sv[j][r] - mrun); sv[j][r] = p; rs += p; }
        rs += __shfl_xor(rs, 16);
        rs += __shfl_xor(rs, 32);
        lrun += rs;
        u32 pk[4][2];
#pragma unroll
        for (int j = 0; j < 4; j++) {
            pk[j][0] = pack2bf(sv[j][0], sv[j][1]);
            pk[j][1] = pack2bf(sv[j][2], sv[j][3]);
        }
        int laneA = (((2 * quad) & 3) << 4) + l15;
        int laneB = (((2 * quad + 1) & 3) << 4) + l15;
        bool hi = (quad & 2) != 0;
#pragma unroll
        for (int c2 = 0; c2 < 2; c2++) {
            u32 a0 = __shfl(pk[2 * c2][0], laneA),     a1 = __shfl(pk[2 * c2][1], laneA);
            u32 b0 = __shfl(pk[2 * c2 + 1][0], laneA), b1 = __shfl(pk[2 * c2 + 1][1], laneA);
            u32 a2 = __shfl(pk[2 * c2][0], laneB),     a3 = __shfl(pk[2 * c2][1], laneB);
            u32 b2 = __shfl(pk[2 * c2 + 1][0], laneB), b3 = __shfl(pk[2 * c2 + 1][1], laneB);
            union { u32 d[4]; bf16x8 v8; } pf;
            pf.d[0] = hi ? b0 : a0;
            pf.d[1] = hi ? b1 : a1;
            pf.d[2] = hi ? b2 : a2;
            pf.d[3] = hi ? b3 : a3;
#pragma unroll
            for (int jt = 0; jt < 8; jt++) {
                bf16x8 vf = *(const bf16x8*)&Vts[(jt * 16 + l15) * VT_STRIDE + c2 * 32 + quad * 8];
                acc_o[jt] = GMFMA(vf, pf.v8, acc_o[jt], 0, 0, 0);
            }
        }
    }
    {
        int row = w * 16 + l15;
        unsigned short* op = Opart + (size_t)flat * 16384 + row * 128;
#pragma unroll
        for (int jt = 0; jt < 8; jt++) {
            uint2 o;
            o.x = pack2bf(acc_o[jt][0], acc_o[jt][1]);
            o.y = pack2bf(acc_o[jt][2], acc_o[jt][3]);
            *(uint2*)(op + jt * 16 + quad * 4) = o;
        }
        if (quad == 0) {
            Mbuf[(size_t)flat * 128 + row] = mrun;
            Lbuf[(size_t)flat * 128 + row] = lrun;
        }
    }
}

// ---------------- combine: merge <=4 chunk partials, normalize, write attnb ----------
__global__ __launch_bounds__(256) void attn_combine_k(const unsigned short* __restrict__ Opart,
                                                      const float* __restrict__ Mbuf,
                                                      const float* __restrict__ Lbuf,
                                                      unsigned short* __restrict__ attnb) {
    int q64 = blockIdx.x, h = blockIdx.y, b = blockIdx.z;
    int qt = q64 >> 1, half = q64 & 1;
    int nch = (qt >> 2) + 1;
    int F = 0;
    for (int q = 0; q < qt; q++) F += (q >> 2) + 1;
    int flat0 = (b * NH + h) * 40 + F;
    int t = threadIdx.x;
    int row = t >> 2, d0 = (t & 3) * 32;
    int row128 = half * 64 + row;
    float mc[4], lc[4], wgt[4];
    float mstar = -1e30f;
#pragma unroll
    for (int c = 0; c < 4; c++) {
        if (c < nch) {
            mc[c] = Mbuf[(size_t)(flat0 + c) * 128 + row128];
            lc[c] = Lbuf[(size_t)(flat0 + c) * 128 + row128];
        } else { mc[c] = -1e30f; lc[c] = 0.f; }
        mstar = fmaxf(mstar, mc[c]);
    }
    float L = 0.f;
#pragma unroll
    for (int c = 0; c < 4; c++) { wgt[c] = __expf(mc[c] - mstar); L += wgt[c] * lc[c]; }
    float invL = 1.f / L;
    float acc[32];
#pragma unroll
    for (int j = 0; j < 32; j++) acc[j] = 0.f;
#pragma unroll
    for (int c = 0; c < 4; c++) {
        if (c < nch) {
            const unsigned short* src = Opart + (size_t)(flat0 + c) * 16384 + row128 * 128 + d0;
            float wc = wgt[c];
#pragma unroll
            for (int g = 0; g < 4; g++) {
                uint4 u = *(const uint4*)(src + g * 8);
                const unsigned short* sp = (const unsigned short*)&u;
#pragma unroll
                for (int j = 0; j < 8; j++) acc[g * 8 + j] += wc * bf2f(sp[j]);
            }
        }
    }
    unsigned short* dst = attnb + (size_t)(b * SEQ + q64 * 64 + row) * 2048 + h * 128 + d0;
#pragma unroll
    for (int g = 0; g < 4; g++) {
        uint4 o;
        unsigned short* sp = (unsigned short*)&o;
#pragma unroll
        for (int j = 0; j < 8; j++) sp[j] = f2bf(acc[g * 8 + j] * invL);
        *(uint4*)(dst + g * 8) = o;
    }
}

// =====================================================================
extern "C" void kernel_launch(void* const* d_in, const int* in_sizes, int n_in,
                              void* d_out, int out_size, void* d_ws, size_t ws_size,
                              hipStream_t stream) {
    const float* hs     = (const float*)d_in[0];
    const float* cosb   = (const float*)d_in[1];
    const float* sinb   = (const float*)d_in[2];
    const float* w_q_a  = (const float*)d_in[3];
    const float* q_ln   = (const float*)d_in[4];
    const float* w_q_b  = (const float*)d_in[5];
    const float* w_kv_a = (const float*)d_in[6];
    const float* kv_ln  = (const float*)d_in[7];
    const float* w_kv_b = (const float*)d_in[8];
    const float* w_o    = (const float*)d_in[9];
    float* out = (float*)d_out;

    char* base = (char*)d_ws;
    size_t off = 0;
    auto take = [&](size_t bytes) { void* p = base + off; off += (bytes + 255) & ~(size_t)255; return p; };
    unsigned short* wqabT = (unsigned short*)take((size_t)2112 * 2048 * 2);  // w_q_a^T ++ w_kv_a^T
    unsigned short* wqbT  = (unsigned short*)take((size_t)3072 * 1536 * 2);
    unsigned short* wkvbT = (unsigned short*)take((size_t)4096 * 512 * 2);
    unsigned short* woT   = (unsigned short*)take((size_t)2048 * 2048 * 2);
    unsigned short* hsb   = (unsigned short*)take((size_t)TT * DD * 2);
    unsigned short* qab   = (unsigned short*)take((size_t)TT * 2112 * 2);   // [q_a | ckv] bf16
    unsigned short* qan   = (unsigned short*)take((size_t)TT * 1536 * 2);
    unsigned short* ckvn  = (unsigned short*)take((size_t)TT * 512 * 2);
    unsigned short* kpe   = (unsigned short*)take((size_t)TT * 64 * 2);
    unsigned short* qb3   = (unsigned short*)take((size_t)TT * 3072 * 2);   // q bf16 (pre-rope)
    unsigned short* Qbuf  = (unsigned short*)take((size_t)TT * NH * HEADD * 2);
    unsigned short* Kb2   = (unsigned short*)take((size_t)32 * 32 * 64 * KS_STRIDE * 2);
    unsigned short* Vt2   = (unsigned short*)take((size_t)32 * 32 * 128 * VT_STRIDE * 2);
    unsigned short* attnb = (unsigned short*)take((size_t)TT * 2048 * 2);
    unsigned short* Opart = (unsigned short*)take((size_t)1280 * 16384 * 2);
    float* Mbuf = (float*)take((size_t)1280 * 128 * 4);
    float* Lbuf = (float*)take((size_t)1280 * 128 * 4);

    // 0. activations + weights to bf16 (weights transposed to [N,K])
    cvt_bf16_k<<<(TT * DD) / 1024, 256, 0, stream>>>(hs, hsb, TT * DD);
    transpose_cvt_k<<<dim3(1536 / 32, 2048 / 32), 256, 0, stream>>>(w_q_a, wqabT, 2048, 1536);
    transpose_cvt_k<<<dim3(18, 2048 / 32), 256, 0, stream>>>(w_kv_a, wqabT + (size_t)1536 * 2048, 2048, 576);
    transpose_cvt_k<<<dim3(3072 / 32, 1536 / 32), 256, 0, stream>>>(w_q_b, wqbT, 1536, 3072);
    transpose_cvt_k<<<dim3(4096 / 32, 512 / 32), 256, 0, stream>>>(w_kv_b, wkvbT, 512, 4096);
    transpose_cvt_k<<<dim3(2048 / 32, 2048 / 32), 256, 0, stream>>>(w_o, woT, 2048, 2048);

    // 1. [q_a | ckv] = hs @ [w_q_a | w_kv_a]
    //    core: cols 0..2047 via 128x256 pipelined GEMM (grid 256 = 1/CU exact)
    //    strip: cols 2048..2111 via m97 kernel (ldc=2112)
    gemm256_k<256, unsigned short><<<dim3(8, 32), 512, 0, stream>>>(hsb, wqabT, qab, 4096, 2112, 2048);
    gemm_bf16o_k<<<dim3(1, 32), 256, 0, stream>>>(hsb, wqabT + (size_t)2048 * 2048, qab + 2048,
                                                  4096, 64, 2048, 2112);
    rmsnorm_bf_k<<<4096, 256, 0, stream>>>(qab, q_ln, qan);
    kvprep_bf_k<<<4096, 256, 0, stream>>>(qab, kv_ln, cosb, sinb, ckvn, kpe);
    // 2. q = qan @ w_q_b ; BN=192 -> grid 512
    gemm256_k<192, unsigned short><<<dim3(16, 32), 512, 0, stream>>>(qan, wqbT, qb3, 4096, 3072, 1536);
    qprep_bf_k<<<4096, 256, 0, stream>>>(qb3, cosb, sinb, Qbuf);
    // 3. kv GEMM with fused split epilogue -> Kb2 (nope) + Vt2 (transposed)
    gemm_kv_k<<<dim3(32, 32), 256, 0, stream>>>(ckvn, wkvbT, Kb2, Vt2);
    kpe_fill_k<<<4096, 256, 0, stream>>>(kpe, Kb2);
    // 4. split-K attention + combine
    attn_mfma_k<<<dim3(40, 16, 2), 512, 0, stream>>>(Qbuf, Kb2, Vt2, Opart, Mbuf, Lbuf);
    attn_combine_k<<<dim3(32, 16, 2), 256, 0, stream>>>(Opart, Mbuf, Lbuf, attnb);
    // 5. out = attn @ w_o (fp32 out), grid 256 = 1/CU exact
    gemm256_k<256, float><<<dim3(8, 32), 512, 0, stream>>>(attnb, woT, out, 4096, 2048, 2048);
}

// Round 6
// 491.071 us; speedup vs baseline: 1.0685x; 1.0685x over previous
//
#include <hip/hip_runtime.h>
#include <cstdint>
#include <cstddef>

// Shapes are fixed by setup_inputs(): T=4096, D=2048, B=2, S=2048.
#define TT 4096
#define DD 2048
#define NH 16
#define HEADD 192
#define NOPE 128
#define VDIM 128
#define SEQ 2048

typedef __bf16 bf16x8 __attribute__((ext_vector_type(8)));
typedef float f32x4 __attribute__((ext_vector_type(4)));
typedef unsigned int u32;

__device__ __forceinline__ float bf2f(unsigned short u) {
    union { unsigned int i; float f; } v; v.i = ((unsigned int)u) << 16; return v.f;
}
__device__ __forceinline__ unsigned short f2bf(float f) {
    union { float f; unsigned int i; } v; v.f = f;
    unsigned int r = v.i + 0x7FFFu + ((v.i >> 16) & 1u);
    return (unsigned short)(r >> 16);
}
__device__ __forceinline__ u32 pack2bf(float a, float b) {
    return (u32)f2bf(a) | ((u32)f2bf(b) << 16);
}
// async global->LDS, 16B per lane; LDS dest = wave-uniform base + lane*16
__device__ __forceinline__ void gload16(const unsigned short* g, unsigned short* l) {
    __builtin_amdgcn_global_load_lds((const __attribute__((address_space(1))) u32*)g,
                                     (__attribute__((address_space(3))) u32*)l, 16, 0, 0);
}

#define GMFMA __builtin_amdgcn_mfma_f32_16x16x32_bf16

// ---------------- fp32 -> bf16 elementwise ----------------
__global__ __launch_bounds__(256) void cvt_bf16_k(const float* __restrict__ x,
                                                  unsigned short* __restrict__ y, int n) {
    int i = (blockIdx.x * 256 + threadIdx.x) * 4;
    if (i < n) {
        float4 v = *(const float4*)(x + i);
        uint2 o;
        o.x = pack2bf(v.x, v.y);
        o.y = pack2bf(v.z, v.w);
        *(uint2*)(y + i) = o;
    }
}

// ---------------- W[K,N] fp32 -> Wt[N,K] bf16 ----------------
__global__ __launch_bounds__(256) void transpose_cvt_k(const float* __restrict__ W,
                                                       unsigned short* __restrict__ Wt,
                                                       int K, int N) {
    __shared__ float tile[32][33];
    int n0 = blockIdx.x * 32, k0 = blockIdx.y * 32;
    int t = threadIdx.x, lr = t >> 5, lc = t & 31;
#pragma unroll
    for (int p = 0; p < 4; p++) {
        int k = k0 + lr + p * 8, n = n0 + lc;
        tile[lr + p * 8][lc] = (k < K && n < N) ? W[(size_t)k * N + n] : 0.f;
    }
    __syncthreads();
#pragma unroll
    for (int p = 0; p < 4; p++) {
        int n = n0 + lr + p * 8, k = k0 + lc;
        if (n < N && k < K) Wt[(size_t)n * K + k] = f2bf(tile[lc][lr + p * 8]);
    }
}

// ======================================================================
// 128x256 double-buffered 8-wave GEMM, BK=64 (round-4 form: best measured).
// Per K-tile: vmcnt(0) gate -> phase0 {stage A+B/2 of kt+1, ds_read m-half0 +
// all B frags, MFMA} -> mid barrier -> phase1 {stage B rest, ds_read m-half1,
// MFMA}. T2 swizzle: (r,c) stored at col c ^ ((r&7)*8); inverse pre-applied
// to the per-lane GLOBAL source so the linear gload_lds write lands swizzled.
// ======================================================================
template <int BN, typename OT>
__global__ __launch_bounds__(512) void gemm256_k(const unsigned short* __restrict__ A,
                                                 const unsigned short* __restrict__ Bt,
                                                 OT* __restrict__ C,
                                                 int M, int N, int K) {
    constexpr int NREP = BN / 64;
    constexpr int NB = BN / 64;
    constexpr int TILE_E = 8192 + BN * 64;
    __shared__ __align__(16) unsigned short lds[2 * TILE_E];
    const int t = threadIdx.x;
    const int w = t >> 6, lane = t & 63;
    const int wr = w >> 2, wc = w & 3;
    const int l15 = lane & 15, quad = lane >> 4;
    const int bm = blockIdx.y * 128, bn = blockIdx.x * BN;
    const int srow = w * 8 + (lane >> 3);
    const int scol = 8 * ((lane & 7) ^ (lane >> 3));
    const unsigned short* Ag = A + (size_t)(bm + srow) * K + scol;
    const unsigned short* Bg = Bt + (size_t)(bn + srow) * K + scol;
    const int rc0 = (quad * 8) ^ ((l15 & 7) * 8);
    const int rc1 = (32 + quad * 8) ^ ((l15 & 7) * 8);
    f32x4 acc[4][NREP];
    f32x4 zero = {0.f, 0.f, 0.f, 0.f};
#pragma unroll
    for (int i = 0; i < 4; i++)
#pragma unroll
        for (int n = 0; n < NREP; n++) acc[i][n] = zero;
    const int NT = K >> 6;
#pragma unroll
    for (int c = 0; c < 2; c++)
        gload16(Ag + (size_t)c * 64 * K, &lds[c * 4096 + w * 512]);
#pragma unroll
    for (int c = 0; c < NB; c++)
        gload16(Bg + (size_t)c * 64 * K, &lds[8192 + c * 4096 + w * 512]);

    for (int kt = 0; kt < NT; kt++) {
        const int cb = (kt & 1) * TILE_E;
        const int nb = TILE_E - cb;
        const bool more = (kt + 1) < NT;
        asm volatile("s_waitcnt vmcnt(0)" ::: "memory");
        __builtin_amdgcn_s_barrier();
        asm volatile("" ::: "memory");
        const unsigned short* Agk = Ag + (size_t)(kt + 1) * 64;
        const unsigned short* Bgk = Bg + (size_t)(kt + 1) * 64;
        if (more) {
            gload16(Agk, &lds[nb + w * 512]);
            gload16(Agk + (size_t)64 * K, &lds[nb + 4096 + w * 512]);
#pragma unroll
            for (int c = 0; c < NB / 2; c++)
                gload16(Bgk + (size_t)c * 64 * K, &lds[nb + 8192 + c * 4096 + w * 512]);
        }
        bf16x8 a0[2][2], b[NREP][2];
#pragma unroll
        for (int j = 0; j < 2; j++) {
            int rl = wr * 64 + j * 16 + l15;
            a0[j][0] = *(const bf16x8*)&lds[cb + rl * 64 + rc0];
            a0[j][1] = *(const bf16x8*)&lds[cb + rl * 64 + rc1];
        }
#pragma unroll
        for (int n = 0; n < NREP; n++) {
            int rl = wc * (BN / 4) + n * 16 + l15;
            b[n][0] = *(const bf16x8*)&lds[cb + 8192 + rl * 64 + rc0];
            b[n][1] = *(const bf16x8*)&lds[cb + 8192 + rl * 64 + rc1];
        }
        __builtin_amdgcn_s_setprio(1);
#pragma unroll
        for (int j = 0; j < 2; j++)
#pragma unroll
            for (int n = 0; n < NREP; n++) {
                acc[j][n] = GMFMA(a0[j][0], b[n][0], acc[j][n], 0, 0, 0);
                acc[j][n] = GMFMA(a0[j][1], b[n][1], acc[j][n], 0, 0, 0);
            }
        __builtin_amdgcn_s_setprio(0);
        __builtin_amdgcn_s_barrier();
        if (more) {
#pragma unroll
            for (int c = NB / 2; c < NB; c++)
                gload16(Bgk + (size_t)c * 64 * K, &lds[nb + 8192 + c * 4096 + w * 512]);
        }
        bf16x8 a1[2][2];
#pragma unroll
        for (int j = 0; j < 2; j++) {
            int rl = wr * 64 + 32 + j * 16 + l15;
            a1[j][0] = *(const bf16x8*)&lds[cb + rl * 64 + rc0];
            a1[j][1] = *(const bf16x8*)&lds[cb + rl * 64 + rc1];
        }
        __builtin_amdgcn_s_setprio(1);
#pragma unroll
        for (int j = 0; j < 2; j++)
#pragma unroll
            for (int n = 0; n < NREP; n++) {
                acc[2 + j][n] = GMFMA(a1[j][0], b[n][0], acc[2 + j][n], 0, 0, 0);
                acc[2 + j][n] = GMFMA(a1[j][1], b[n][1], acc[2 + j][n], 0, 0, 0);
            }
        __builtin_amdgcn_s_setprio(0);
    }
#pragma unroll
    for (int mi = 0; mi < 4; mi++) {
        int row = bm + wr * 64 + mi * 16 + quad * 4;
#pragma unroll
        for (int n = 0; n < NREP; n++) {
            int col = bn + wc * (BN / 4) + n * 16 + l15;
            OT* cp = C + (size_t)row * N + col;
#pragma unroll
            for (int r = 0; r < 4; r++) {
                float v = acc[mi][n][r];
                if constexpr (sizeof(OT) == 2) cp[(size_t)r * N] = f2bf(v);
                else                            cp[(size_t)r * N] = v;
            }
        }
    }
}

// ======================================================================
// q_b GEMM (M=4096, N=3072, K=1536) with FUSED rope epilogue -> Qbuf.
// Same round-4 loop body at BN=192. Epilogue: bounce the 128x192 tile
// through LDS (free after K-loop), apply rope to cols [128,192) reading
// (even,odd) pairs from LDS, write Qbuf directly. SCALE pre-folded into qan.
// ======================================================================
__global__ __launch_bounds__(512) void gemm192_rope_k(const unsigned short* __restrict__ A,
                                                      const unsigned short* __restrict__ Bt,
                                                      const float* __restrict__ cosb,
                                                      const float* __restrict__ sinb,
                                                      unsigned short* __restrict__ Qb) {
    constexpr int K = 1536, N = 3072;
    constexpr int NREP = 3, NB = 3;
    constexpr int TILE_E = 8192 + 192 * 64;   // 20480
    __shared__ __align__(16) unsigned short lds[2 * TILE_E];  // 80 KB
    const int t = threadIdx.x;
    const int w = t >> 6, lane = t & 63;
    const int wr = w >> 2, wc = w & 3;
    const int l15 = lane & 15, quad = lane >> 4;
    const int bm = blockIdx.y * 128, bn = blockIdx.x * 192;
    const int srow = w * 8 + (lane >> 3);
    const int scol = 8 * ((lane & 7) ^ (lane >> 3));
    const unsigned short* Ag = A + (size_t)(bm + srow) * K + scol;
    const unsigned short* Bg = Bt + (size_t)(bn + srow) * K + scol;
    const int rc0 = (quad * 8) ^ ((l15 & 7) * 8);
    const int rc1 = (32 + quad * 8) ^ ((l15 & 7) * 8);
    f32x4 acc[4][NREP];
    f32x4 zero = {0.f, 0.f, 0.f, 0.f};
#pragma unroll
    for (int i = 0; i < 4; i++)
#pragma unroll
        for (int n = 0; n < NREP; n++) acc[i][n] = zero;
    const int NT = K >> 6;   // 24
#pragma unroll
    for (int c = 0; c < 2; c++)
        gload16(Ag + (size_t)c * 64 * K, &lds[c * 4096 + w * 512]);
#pragma unroll
    for (int c = 0; c < NB; c++)
        gload16(Bg + (size_t)c * 64 * K, &lds[8192 + c * 4096 + w * 512]);

    for (int kt = 0; kt < NT; kt++) {
        const int cb = (kt & 1) * TILE_E;
        const int nb = TILE_E - cb;
        const bool more = (kt + 1) < NT;
        asm volatile("s_waitcnt vmcnt(0)" ::: "memory");
        __builtin_amdgcn_s_barrier();
        asm volatile("" ::: "memory");
        const unsigned short* Agk = Ag + (size_t)(kt + 1) * 64;
        const unsigned short* Bgk = Bg + (size_t)(kt + 1) * 64;
        if (more) {
            gload16(Agk, &lds[nb + w * 512]);
            gload16(Agk + (size_t)64 * K, &lds[nb + 4096 + w * 512]);
            gload16(Bgk, &lds[nb + 8192 + w * 512]);
        }
        bf16x8 a0[2][2], b[NREP][2];
#pragma unroll
        for (int j = 0; j < 2; j++) {
            int rl = wr * 64 + j * 16 + l15;
            a0[j][0] = *(const bf16x8*)&lds[cb + rl * 64 + rc0];
            a0[j][1] = *(const bf16x8*)&lds[cb + rl * 64 + rc1];
        }
#pragma unroll
        for (int n = 0; n < NREP; n++) {
            int rl = wc * 48 + n * 16 + l15;
            b[n][0] = *(const bf16x8*)&lds[cb + 8192 + rl * 64 + rc0];
            b[n][1] = *(const bf16x8*)&lds[cb + 8192 + rl * 64 + rc1];
        }
        __builtin_amdgcn_s_setprio(1);
#pragma unroll
        for (int j = 0; j < 2; j++)
#pragma unroll
            for (int n = 0; n < NREP; n++) {
                acc[j][n] = GMFMA(a0[j][0], b[n][0], acc[j][n], 0, 0, 0);
                acc[j][n] = GMFMA(a0[j][1], b[n][1], acc[j][n], 0, 0, 0);
            }
        __builtin_amdgcn_s_setprio(0);
        __builtin_amdgcn_s_barrier();
        if (more) {
#pragma unroll
            for (int c = 1; c < NB; c++)
                gload16(Bgk + (size_t)c * 64 * K, &lds[nb + 8192 + c * 4096 + w * 512]);
        }
        bf16x8 a1[2][2];
#pragma unroll
        for (int j = 0; j < 2; j++) {
            int rl = wr * 64 + 32 + j * 16 + l15;
            a1[j][0] = *(const bf16x8*)&lds[cb + rl * 64 + rc0];
            a1[j][1] = *(const bf16x8*)&lds[cb + rl * 64 + rc1];
        }
        __builtin_amdgcn_s_setprio(1);
#pragma unroll
        for (int j = 0; j < 2; j++)
#pragma unroll
            for (int n = 0; n < NREP; n++) {
                acc[2 + j][n] = GMFMA(a1[j][0], b[n][0], acc[2 + j][n], 0, 0, 0);
                acc[2 + j][n] = GMFMA(a1[j][1], b[n][1], acc[2 + j][n], 0, 0, 0);
            }
        __builtin_amdgcn_s_setprio(0);
    }
    // ---- fused rope epilogue ----
    __syncthreads();                       // all waves done with K-loop LDS reads
    unsigned short* Ct = lds;              // 128 x 200 bounce tile (50 KB)
#pragma unroll
    for (int mi = 0; mi < 4; mi++) {
        int rl = wr * 64 + mi * 16 + quad * 4;
#pragma unroll
        for (int n = 0; n < NREP; n++) {
            int cl = wc * 48 + n * 16 + l15;
#pragma unroll
            for (int r = 0; r < 4; r++)
                Ct[(rl + r) * 200 + cl] = f2bf(acc[mi][n][r]);
        }
    }
    __syncthreads();
    {
        int r = t >> 2, cg = t & 3;        // row 0..127, 48-col group 0..3
        int trow = bm + r;
        int h = blockIdx.x;                // head
        const float* cr = cosb + (size_t)trow * 32;
        const float* sn = sinb + (size_t)trow * 32;
        unsigned short* dst = Qb + ((size_t)trow * NH + h) * HEADD + cg * 48;
        __align__(16) unsigned short tmp[48];
        const unsigned short* rowp = &Ct[r * 200];
        if (cg < 2) {
#pragma unroll
            for (int i = 0; i < 48; i++) tmp[i] = rowp[cg * 48 + i];
        } else if (cg == 2) {
#pragma unroll
            for (int i = 0; i < 32; i++) tmp[i] = rowp[96 + i];
            const unsigned short* pe = rowp + 128;
#pragma unroll
            for (int jj = 0; jj < 16; jj++) {
                float e = bf2f(pe[2 * jj]), o = bf2f(pe[2 * jj + 1]);
                tmp[32 + jj] = f2bf(e * cr[jj] - o * sn[jj]);
            }
        } else {
            const unsigned short* pe = rowp + 128;
#pragma unroll
            for (int jj = 16; jj < 32; jj++) {
                float e = bf2f(pe[2 * jj]), o = bf2f(pe[2 * jj + 1]);
                tmp[jj - 16] = f2bf(e * cr[jj] - o * sn[jj]);
            }
#pragma unroll
            for (int jj = 0; jj < 32; jj++) {
                float e = bf2f(pe[2 * jj]), o = bf2f(pe[2 * jj + 1]);
                tmp[16 + jj] = f2bf(o * cr[jj] + e * sn[jj]);
            }
        }
#pragma unroll
        for (int g = 0; g < 6; g++)
            *(uint4*)(dst + g * 8) = *(const uint4*)(&tmp[g * 8]);
    }
}

// Attention-ready padded tiled layouts:
//   Kb2 [bh][kt=32][64 rows][KS_STRIDE=200]
//   Vt2 [bh][kt=32][128 dims][VT_STRIDE=72]
#define KS_STRIDE 200
#define VT_STRIDE 72
#define CS_STRIDE 132

// ---------------- kv GEMM, fused K/V-split epilogue + kpe broadcast ---------------
__global__ __launch_bounds__(256) void gemm_kv_k(const unsigned short* __restrict__ A,
                                                 const unsigned short* __restrict__ Bt,
                                                 const unsigned short* __restrict__ kpe,
                                                 unsigned short* __restrict__ Kb2,
                                                 unsigned short* __restrict__ Vt2) {
    const int K = 512;
    __shared__ __align__(16) unsigned short smem[128 * CS_STRIDE];  // 33.8 KB
    unsigned short* As = smem;
    unsigned short* Bs = smem + 128 * 32;
    unsigned short* Cs = smem;
    int bm = blockIdx.y * 128, bn = blockIdx.x * 128;
    int t = threadIdx.x;
    int wave = t >> 6, lane = t & 63;
    int wr = (wave >> 1) * 64, wc = (wave & 1) * 64;
    int l15 = lane & 15, quad = lane >> 4;
    f32x4 acc[4][4];
    f32x4 zero = {0.f, 0.f, 0.f, 0.f};
#pragma unroll
    for (int i = 0; i < 4; i++)
#pragma unroll
        for (int j = 0; j < 4; j++) acc[i][j] = zero;
    int r0 = 16 * (2 * wave) + (lane >> 2);
    int cOff = (lane & 3) * 8;
    const unsigned short* gA0 = A + (size_t)(bm + r0) * K + cOff;
    const unsigned short* gA1 = A + (size_t)(bm + r0 + 16) * K + cOff;
    const unsigned short* gB0 = Bt + (size_t)(bn + r0) * K + cOff;
    const unsigned short* gB1 = Bt + (size_t)(bn + r0 + 16) * K + cOff;
    unsigned short* lA0 = &As[(2 * wave) * 512];
    unsigned short* lA1 = &As[(2 * wave + 1) * 512];
    unsigned short* lB0 = &Bs[(2 * wave) * 512];
    unsigned short* lB1 = &Bs[(2 * wave + 1) * 512];
    for (int k0 = 0; k0 < K; k0 += 32) {
        gload16(gA0 + k0, lA0);
        gload16(gA1 + k0, lA1);
        gload16(gB0 + k0, lB0);
        gload16(gB1 + k0, lB1);
        __syncthreads();
        bf16x8 af[4], bfr[4];
#pragma unroll
        for (int i = 0; i < 4; i++)
            af[i] = *(const bf16x8*)&As[(wr + i * 16 + l15) * 32 + quad * 8];
#pragma unroll
        for (int j = 0; j < 4; j++)
            bfr[j] = *(const bf16x8*)&Bs[(wc + j * 16 + l15) * 32 + quad * 8];
#pragma unroll
        for (int i = 0; i < 4; i++)
#pragma unroll
            for (int j = 0; j < 4; j++)
                acc[i][j] = GMFMA(af[i], bfr[j], acc[i][j], 0, 0, 0);
        __syncthreads();
    }
#pragma unroll
    for (int i = 0; i < 4; i++) {
        int lr = wr + i * 16 + quad * 4;
#pragma unroll
        for (int j = 0; j < 4; j++) {
            int lc = wc + j * 16 + l15;
#pragma unroll
            for (int r = 0; r < 4; r++)
                Cs[(lr + r) * CS_STRIDE + lc] = f2bf(acc[i][j][r]);
        }
    }
    __syncthreads();
    int hh = bn >> 8;
    bool isV = (bn & 255) != 0;
    if (!isV) {
        int row = t >> 1, halfc = t & 1;
        int gs = bm + row;
        int b2 = gs >> 11, s2 = gs & 2047;
        unsigned short* dpb = Kb2 +
            ((size_t)((b2 * NH + hh) * 32 + (s2 >> 6)) * 64 + (s2 & 63)) * KS_STRIDE;
        const unsigned short* sp = &Cs[row * CS_STRIDE + halfc * 64];
        unsigned short* dp = dpb + halfc * 64;
#pragma unroll
        for (int g = 0; g < 8; g++)
            *(uint4*)(dp + g * 8) = *(const uint4*)(sp + g * 8);
        if (halfc) {
            // fused kpe broadcast: dims [128,192) from the contiguous kpe row
            const unsigned short* kp = kpe + (size_t)gs * 64;
            unsigned short* dq = dpb + 128;
#pragma unroll
            for (int g = 0; g < 8; g++)
                *(uint4*)(dq + g * 8) = *(const uint4*)(kp + g * 8);
        }
    } else {
        int kth = t >> 7, dim = t & 127;
        int gs0 = bm + kth * 64;
        int b2 = gs0 >> 11, s20 = gs0 & 2047;
        unsigned short* dp = Vt2 +
            ((size_t)((b2 * NH + hh) * 32 + (s20 >> 6)) * 128 + dim) * VT_STRIDE;
#pragma unroll
        for (int g = 0; g < 8; g++) {
            uint4 o;
            unsigned short* op = (unsigned short*)&o;
#pragma unroll
            for (int q2 = 0; q2 < 8; q2++)
                op[q2] = Cs[(kth * 64 + g * 8 + q2) * CS_STRIDE + dim];
            *(uint4*)(dp + g * 8) = o;
        }
    }
}

// ------- merged norms: rmsnorm(q_a)*SCALE -> qan ; rmsnorm(ckv) -> ckvn ; rope kpe -----
// qab row stride is 2304 (padded). SCALE = 192^-0.5 folded here (linear through GEMM+rope).
__global__ __launch_bounds__(256) void norms_k(const unsigned short* __restrict__ qab,
                                               const float* __restrict__ qw,
                                               const float* __restrict__ kw,
                                               const float* __restrict__ cosb,
                                               const float* __restrict__ sinb,
                                               unsigned short* __restrict__ qan,
                                               unsigned short* __restrict__ ckvn,
                                               unsigned short* __restrict__ kpe) {
    const float QSCALE = 0.07216878364870323f;
    int row = blockIdx.x, t = threadIdx.x;
    const unsigned short* xr = qab + (size_t)row * 2304;
    float s1 = 0.f, s2 = 0.f;
    for (int i = t; i < 1536; i += 256) { float v = bf2f(xr[i]); s1 += v * v; }
#pragma unroll
    for (int i = t; i < 512; i += 256) { float v = bf2f(xr[1536 + i]); s2 += v * v; }
    __shared__ float r1[256], r2[256];
    r1[t] = s1; r2[t] = s2; __syncthreads();
    for (int o = 128; o > 0; o >>= 1) {
        if (t < o) { r1[t] += r1[t + o]; r2[t] += r2[t + o]; }
        __syncthreads();
    }
    float sc1 = rsqrtf(r1[0] / 1536.f + 1e-6f) * QSCALE;
    float sc2 = rsqrtf(r2[0] / 512.f + 1e-6f);
    unsigned short* y1 = qan + (size_t)row * 1536;
    for (int i = t; i < 1536; i += 256) y1[i] = f2bf(bf2f(xr[i]) * sc1 * qw[i]);
    unsigned short* y2 = ckvn + (size_t)row * 512;
#pragma unroll
    for (int i = t; i < 512; i += 256) y2[i] = f2bf(bf2f(xr[1536 + i]) * sc2 * kw[i]);
    if (t < 32) {
        float e = bf2f(xr[2048 + 2 * t]), o = bf2f(xr[2048 + 2 * t + 1]);
        float c = cosb[row * 32 + t], sn = sinb[row * 32 + t];
        kpe[row * 64 + t]      = f2bf(e * c - o * sn);
        kpe[row * 64 + 32 + t] = f2bf(o * c + e * sn);
    }
}

// ---------------- split-K causal flash attention, MFMA bf16, S^T form ----------------
// Round-3 verified version (do not touch).
__global__ __launch_bounds__(512) void attn_mfma_k(const unsigned short* __restrict__ Qb,
                                                   const unsigned short* __restrict__ Kb2,
                                                   const unsigned short* __restrict__ Vt2,
                                                   unsigned short* __restrict__ Opart,
                                                   float* __restrict__ Mbuf,
                                                   float* __restrict__ Lbuf) {
    __shared__ __align__(16) unsigned short Ks[64 * KS_STRIDE];    // 25.6 KB
    __shared__ __align__(16) unsigned short Vts[128 * VT_STRIDE];  // 18.4 KB
    int xe = 39 - blockIdx.x;
    int h  = blockIdx.y;
    int b  = blockIdx.z;
    int qt = 0, accn = 0;
    while (true) { int c = (qt >> 2) + 1; if (xe < accn + c) break; accn += c; qt++; }
    int chunk = xe - accn;
    int t = threadIdx.x;
    int w = t >> 6, lane = t & 63;
    int l15 = lane & 15, quad = lane >> 4;
    int bh = b * NH + h;
    int q0 = b * SEQ + qt * 128;
    int qglob = qt * 128 + w * 16 + l15;
    int flat = bh * 40 + xe;

    bf16x8 qf[6];
    {
        const unsigned short* qbase = Qb + ((size_t)(q0 + w * 16 + l15) * NH + h) * HEADD + quad * 8;
#pragma unroll
        for (int c = 0; c < 6; c++)
            qf[c] = *(const bf16x8*)(qbase + c * 32);
    }
    f32x4 acc_o[8];
    f32x4 zero = {0.f, 0.f, 0.f, 0.f};
#pragma unroll
    for (int j = 0; j < 8; j++) acc_o[j] = zero;
    float mrun = -1e30f, lrun = 0.f;

    int kt0 = chunk * 8, kt1 = min(kt0 + 7, 2 * qt + 1);
    int cbeg = w * 5 + min(w, 3), cnt = (w < 3) ? 6 : 5;
    for (int kt = kt0; kt <= kt1; kt++) {
        __syncthreads();
        {
            const unsigned short* kg = Kb2 + ((size_t)bh * 32 + kt) * (64 * KS_STRIDE) + lane * 8;
            const unsigned short* vg = Vt2 + ((size_t)bh * 32 + kt) * (128 * VT_STRIDE) + lane * 8;
            for (int c = cbeg; c < cbeg + cnt; c++) {
                if (c < 25) gload16(kg + c * 512, &Ks[c * 512]);
                else        gload16(vg + (c - 25) * 512, &Vts[(c - 25) * 512]);
            }
        }
        __syncthreads();
        f32x4 acc_s[4];
#pragma unroll
        for (int j = 0; j < 4; j++) acc_s[j] = zero;
#pragma unroll
        for (int c = 0; c < 6; c++) {
#pragma unroll
            for (int j = 0; j < 4; j++) {
                bf16x8 kf = *(const bf16x8*)&Ks[(j * 16 + l15) * KS_STRIDE + c * 32 + quad * 8];
                acc_s[j] = GMFMA(kf, qf[c], acc_s[j], 0, 0, 0);
            }
        }
        float sv[4][4];
        const bool needmask = (kt * 64 + 63) > (qt * 128 + w * 16);
        if (needmask) {
#pragma unroll
            for (int j = 0; j < 4; j++) {
                int kbase = kt * 64 + j * 16 + quad * 4;
#pragma unroll
                for (int r = 0; r < 4; r++)
                    sv[j][r] = (kbase + r > qglob) ? -1e30f : acc_s[j][r];
            }
        } else {
#pragma unroll
            for (int j = 0; j < 4; j++)
#pragma unroll
                for (int r = 0; r < 4; r++) sv[j][r] = acc_s[j][r];
        }
        float v = sv[0][0];
#pragma unroll
        for (int j = 0; j < 4; j++)
#pragma unroll
            for (int r = 0; r < 4; r++) v = fmaxf(v, sv[j][r]);
        v = fmaxf(v, __shfl_xor(v, 16));
        v = fmaxf(v, __shfl_xor(v, 32));
        if (!__all(v - mrun <= 8.f)) {
            float mnew = fmaxf(mrun, v);
            float alpha = __expf(mrun - mnew);
            mrun = mnew;
            lrun *= alpha;
#pragma unroll
            for (int jt = 0; jt < 8; jt++)
#pragma unroll
                for (int r = 0; r < 4; r++) acc_o[jt][r] *= alpha;
        }
        float rs = 0.f;
#pragma unroll
        for (int j = 0; j < 4; j++)
#pragma unroll
            for (int r = 0; r < 4; r++) { float p = __expf(sv[j][r] - mrun); sv[j][r] = p; rs += p; }
        rs += __shfl_xor(rs, 16);
        rs += __shfl_xor(rs, 32);
        lrun += rs;
        u32 pk[4][2];
#pragma unroll
        for (int j = 0; j < 4; j++) {
            pk[j][0] = pack2bf(sv[j][0], sv[j][1]);
            pk[j][1] = pack2bf(sv[j][2], sv[j][3]);
        }
        int laneA = (((2 * quad) & 3) << 4) + l15;
        int laneB = (((2 * quad + 1) & 3) << 4) + l15;
        bool hi = (quad & 2) != 0;
#pragma unroll
        for (int c2 = 0; c2 < 2; c2++) {
            u32 a0 = __shfl(pk[2 * c2][0], laneA),     a1 = __shfl(pk[2 * c2][1], laneA);
            u32 b0 = __shfl(pk[2 * c2 + 1][0], laneA), b1 = __shfl(pk[2 * c2 + 1][1], laneA);
            u32 a2 = __shfl(pk[2 * c2][0], laneB),     a3 = __shfl(pk[2 * c2][1], laneB);
            u32 b2 = __shfl(pk[2 * c2 + 1][0], laneB), b3 = __shfl(pk[2 * c2 + 1][1], laneB);
            union { u32 d[4]; bf16x8 v8; } pf;
            pf.d[0] = hi ? b0 : a0;
            pf.d[1] = hi ? b1 : a1;
            pf.d[2] = hi ? b2 : a2;
            pf.d[3] = hi ? b3 : a3;
#pragma unroll
            for (int jt = 0; jt < 8; jt++) {
                bf16x8 vf = *(const bf16x8*)&Vts[(jt * 16 + l15) * VT_STRIDE + c2 * 32 + quad * 8];
                acc_o[jt] = GMFMA(vf, pf.v8, acc_o[jt], 0, 0, 0);
            }
        }
    }
    {
        int row = w * 16 + l15;
        unsigned short* op = Opart + (size_t)flat * 16384 + row * 128;
#pragma unroll
        for (int jt = 0; jt < 8; jt++) {
            uint2 o;
            o.x = pack2bf(acc_o[jt][0], acc_o[jt][1]);
            o.y = pack2bf(acc_o[jt][2], acc_o[jt][3]);
            *(uint2*)(op + jt * 16 + quad * 4) = o;
        }
        if (quad == 0) {
            Mbuf[(size_t)flat * 128 + row] = mrun;
            Lbuf[(size_t)flat * 128 + row] = lrun;
        }
    }
}

// ---------------- combine: merge <=4 chunk partials, normalize, write attnb ----------
__global__ __launch_bounds__(256) void attn_combine_k(const unsigned short* __restrict__ Opart,
                                                      const float* __restrict__ Mbuf,
                                                      const float* __restrict__ Lbuf,
                                                      unsigned short* __restrict__ attnb) {
    int q64 = blockIdx.x, h = blockIdx.y, b = blockIdx.z;
    int qt = q64 >> 1, half = q64 & 1;
    int nch = (qt >> 2) + 1;
    int F = 0;
    for (int q = 0; q < qt; q++) F += (q >> 2) + 1;
    int flat0 = (b * NH + h) * 40 + F;
    int t = threadIdx.x;
    int row = t >> 2, d0 = (t & 3) * 32;
    int row128 = half * 64 + row;
    float mc[4], lc[4], wgt[4];
    float mstar = -1e30f;
#pragma unroll
    for (int c = 0; c < 4; c++) {
        if (c < nch) {
            mc[c] = Mbuf[(size_t)(flat0 + c) * 128 + row128];
            lc[c] = Lbuf[(size_t)(flat0 + c) * 128 + row128];
        } else { mc[c] = -1e30f; lc[c] = 0.f; }
        mstar = fmaxf(mstar, mc[c]);
    }
    float L = 0.f;
#pragma unroll
    for (int c = 0; c < 4; c++) { wgt[c] = __expf(mc[c] - mstar); L += wgt[c] * lc[c]; }
    float invL = 1.f / L;
    float acc[32];
#pragma unroll
    for (int j = 0; j < 32; j++) acc[j] = 0.f;
#pragma unroll
    for (int c = 0; c < 4; c++) {
        if (c < nch) {
            const unsigned short* src = Opart + (size_t)(flat0 + c) * 16384 + row128 * 128 + d0;
            float wc = wgt[c];
#pragma unroll
            for (int g = 0; g < 4; g++) {
                uint4 u = *(const uint4*)(src + g * 8);
                const unsigned short* sp = (const unsigned short*)&u;
#pragma unroll
                for (int j = 0; j < 8; j++) acc[g * 8 + j] += wc * bf2f(sp[j]);
            }
        }
    }
    unsigned short* dst = attnb + (size_t)(b * SEQ + q64 * 64 + row) * 2048 + h * 128 + d0;
#pragma unroll
    for (int g = 0; g < 4; g++) {
        uint4 o;
        unsigned short* sp = (unsigned short*)&o;
#pragma unroll
        for (int j = 0; j < 8; j++) sp[j] = f2bf(acc[g * 8 + j] * invL);
        *(uint4*)(dst + g * 8) = o;
    }
}

// =====================================================================
extern "C" void kernel_launch(void* const* d_in, const int* in_sizes, int n_in,
                              void* d_out, int out_size, void* d_ws, size_t ws_size,
                              hipStream_t stream) {
    const float* hs     = (const float*)d_in[0];
    const float* cosb   = (const float*)d_in[1];
    const float* sinb   = (const float*)d_in[2];
    const float* w_q_a  = (const float*)d_in[3];
    const float* q_ln   = (const float*)d_in[4];
    const float* w_q_b  = (const float*)d_in[5];
    const float* w_kv_a = (const float*)d_in[6];
    const float* kv_ln  = (const float*)d_in[7];
    const float* w_kv_b = (const float*)d_in[8];
    const float* w_o    = (const float*)d_in[9];
    float* out = (float*)d_out;

    char* base = (char*)d_ws;
    size_t off = 0;
    auto take = [&](size_t bytes) { void* p = base + off; off += (bytes + 255) & ~(size_t)255; return p; };
    unsigned short* wqabT = (unsigned short*)take((size_t)2304 * 2048 * 2);  // w_q_a^T ++ w_kv_a^T (padded to 2304)
    unsigned short* wqbT  = (unsigned short*)take((size_t)3072 * 1536 * 2);
    unsigned short* wkvbT = (unsigned short*)take((size_t)4096 * 512 * 2);
    unsigned short* woT   = (unsigned short*)take((size_t)2048 * 2048 * 2);
    unsigned short* hsb   = (unsigned short*)take((size_t)TT * DD * 2);
    unsigned short* qab   = (unsigned short*)take((size_t)TT * 2304 * 2);   // [q_a | ckv | pad] bf16
    unsigned short* qan   = (unsigned short*)take((size_t)TT * 1536 * 2);
    unsigned short* ckvn  = (unsigned short*)take((size_t)TT * 512 * 2);
    unsigned short* kpe   = (unsigned short*)take((size_t)TT * 64 * 2);
    unsigned short* Qbuf  = (unsigned short*)take((size_t)TT * NH * HEADD * 2);
    unsigned short* Kb2   = (unsigned short*)take((size_t)32 * 32 * 64 * KS_STRIDE * 2);
    unsigned short* Vt2   = (unsigned short*)take((size_t)32 * 32 * 128 * VT_STRIDE * 2);
    unsigned short* attnb = (unsigned short*)take((size_t)TT * 2048 * 2);
    unsigned short* Opart = (unsigned short*)take((size_t)1280 * 16384 * 2);
    float* Mbuf = (float*)take((size_t)1280 * 128 * 4);
    float* Lbuf = (float*)take((size_t)1280 * 128 * 4);

    // 0. activations + weights to bf16 (weights transposed to [N,K])
    cvt_bf16_k<<<(TT * DD) / 1024, 256, 0, stream>>>(hs, hsb, TT * DD);
    transpose_cvt_k<<<dim3(1536 / 32, 2048 / 32), 256, 0, stream>>>(w_q_a, wqabT, 2048, 1536);
    transpose_cvt_k<<<dim3(18, 2048 / 32), 256, 0, stream>>>(w_kv_a, wqabT + (size_t)1536 * 2048, 2048, 576);
    transpose_cvt_k<<<dim3(3072 / 32, 1536 / 32), 256, 0, stream>>>(w_q_b, wqbT, 1536, 3072);
    transpose_cvt_k<<<dim3(4096 / 32, 512 / 32), 256, 0, stream>>>(w_kv_b, wkvbT, 512, 4096);
    transpose_cvt_k<<<dim3(2048 / 32, 2048 / 32), 256, 0, stream>>>(w_o, woT, 2048, 2048);

    // 1. [q_a | ckv | pad] = hs @ [w_q_a | w_kv_a | junk]  (N padded to 2304 = 9x256)
    gemm256_k<256, unsigned short><<<dim3(9, 32), 512, 0, stream>>>(hsb, wqabT, qab, 4096, 2304, 2048);
    norms_k<<<4096, 256, 0, stream>>>(qab, q_ln, kv_ln, cosb, sinb, qan, ckvn, kpe);
    // 2. Qbuf = rope(qan @ w_q_b)  (fused epilogue; SCALE folded into qan)
    gemm192_rope_k<<<dim3(16, 32), 512, 0, stream>>>(qan, wqbT, cosb, sinb, Qbuf);
    // 3. kv GEMM, fused split epilogue + kpe broadcast -> Kb2 + Vt2
    gemm_kv_k<<<dim3(32, 32), 256, 0, stream>>>(ckvn, wkvbT, kpe, Kb2, Vt2);
    // 4. split-K attention + combine
    attn_mfma_k<<<dim3(40, 16, 2), 512, 0, stream>>>(Qbuf, Kb2, Vt2, Opart, Mbuf, Lbuf);
    attn_combine_k<<<dim3(32, 16, 2), 256, 0, stream>>>(Opart, Mbuf, Lbuf, attnb);
    // 5. out = attn @ w_o (fp32 out)
    gemm256_k<256, float><<<dim3(8, 32), 512, 0, stream>>>(attnb, woT, out, 4096, 2048, 2048);
}